// Round 1
// baseline (230.648 us; speedup 1.0000x reference)
//
#include <hip/hip_runtime.h>
#include <hip/hip_bf16.h>

#define TPB 256
#define HW 4096

typedef unsigned int uint32;

// Cooperative crossing search: given hist[NB] (bin index ascending = key ascending),
// find bin b and rank r such that  (#keys in bins > b) < kk <= (#keys in bins >= b),
// r = kk - (#keys in bins > b).  All 256 threads participate.
template<int NB>
__device__ inline void find_crossing(uint32* hist, uint32* chunkSum, uint32 kk,
                                     uint32* sh_bin, uint32* sh_rank)
{
    const int tid = threadIdx.x;
    constexpr int CH = NB / TPB;  // bins per thread
    uint32 s = 0;
#pragma unroll
    for (int j = 0; j < CH; ++j) s += hist[tid * CH + j];
    chunkSum[tid] = s;
    __syncthreads();
    if (tid < 64) {
        uint32 g = 0;
#pragma unroll
        for (int j = 0; j < 4; ++j) g += chunkSum[tid * 4 + j];
        // inclusive suffix sum across the 64 lanes of wave 0
        uint32 suf = g;
#pragma unroll
        for (int d = 1; d < 64; d <<= 1) {
            uint32 v = __shfl_down(suf, d, 64);
            suf += (tid + d < 64) ? v : 0u;
        }
        unsigned long long m = __ballot(suf >= kk);   // non-increasing -> prefix of lanes
        int lstar = 63 - __clzll(m);                  // highest lane with suf >= kk
        uint32 cumAbove = (lstar < 63) ? __shfl(suf, lstar + 1, 64) : 0u;
        if (tid == lstar) {
            uint32 c = cumAbove;
            int bin = lstar * 4 * CH;
            uint32 rank = 1;
            bool done = false;
            for (int cc = lstar * 4 + 3; cc >= lstar * 4 && !done; --cc) {
                uint32 cs = chunkSum[cc];
                if (c + cs >= kk) {
                    for (int b = cc * CH + CH - 1; b >= cc * CH; --b) {
                        uint32 h = hist[b];
                        if (c + h >= kk) { bin = b; rank = kk - c; break; }
                        c += h;
                    }
                    done = true;
                } else {
                    c += cs;
                }
            }
            *sh_bin = (uint32)bin;
            *sh_rank = rank;
        }
    }
    __syncthreads();
}

__global__ void __launch_bounds__(TPB)
topk_blend_kernel(const float* __restrict__ x, const float* __restrict__ taup,
                  const int* __restrict__ kp, float* __restrict__ out, int nrows)
{
    __shared__ uint32 hist[2048];
    __shared__ uint32 chunkSum[TPB];
    __shared__ uint32 sh_bin, sh_rank, sh_cnt, sh_idxcut;

    const int tid = threadIdx.x;
    const int row = blockIdx.x;
    if (row >= nrows) return;

    const float4* xr  = reinterpret_cast<const float4*>(x + (size_t)row * HW);
    float4*       orw = reinterpret_cast<float4*>(out + (size_t)row * HW);

    // ---- load 16 elements/thread (4x float4, coalesced) ----
    float4 v[4];
#pragma unroll
    for (int j = 0; j < 4; ++j) v[j] = xr[tid + j * TPB];

    const uint32 K  = (uint32)(*kp);
    const float tau = *taup;

    // ---- init ----
#pragma unroll
    for (int j = 0; j < 8; ++j) hist[tid + j * TPB] = 0;
    if (tid == 0) { sh_cnt = 0; sh_idxcut = 0xFFFFFFFFu; }
    __syncthreads();

    // |x| bit keys (monotonic for non-negative floats)
    uint32 key[16];
#pragma unroll
    for (int j = 0; j < 4; ++j) {
        const float* pv = reinterpret_cast<const float*>(&v[j]);
#pragma unroll
        for (int l = 0; l < 4; ++l)
            key[j * 4 + l] = __float_as_uint(pv[l]) & 0x7fffffffu;
    }

    // ---- pass 1: bits 30..20 (11 bits) ----
#pragma unroll
    for (int e = 0; e < 16; ++e) atomicAdd(&hist[key[e] >> 20], 1u);
    __syncthreads();
    find_crossing<2048>(hist, chunkSum, K, &sh_bin, &sh_rank);
    const uint32 b1 = sh_bin;
    const uint32 k1 = sh_rank;

    // ---- pass 2: bits 19..9 (11 bits), among keys in bin b1 ----
#pragma unroll
    for (int j = 0; j < 8; ++j) hist[tid + j * TPB] = 0;
    __syncthreads();
#pragma unroll
    for (int e = 0; e < 16; ++e)
        if ((key[e] >> 20) == b1) atomicAdd(&hist[(key[e] >> 9) & 2047u], 1u);
    __syncthreads();
    find_crossing<2048>(hist, chunkSum, k1, &sh_bin, &sh_rank);
    const uint32 b2 = sh_bin;
    const uint32 k2 = sh_rank;
    const uint32 p2 = (b1 << 11) | b2;   // 22-bit prefix

    // ---- pass 3: bits 8..0 (9 bits), among keys matching 22-bit prefix ----
#pragma unroll
    for (int j = 0; j < 2; ++j) hist[tid + j * TPB] = 0;
    __syncthreads();
#pragma unroll
    for (int e = 0; e < 16; ++e)
        if ((key[e] >> 9) == p2) atomicAdd(&hist[key[e] & 511u], 1u);
    __syncthreads();
    find_crossing<512>(hist, chunkSum, k2, &sh_bin, &sh_rank);
    const uint32 b3  = sh_bin;
    const uint32 k3  = sh_rank;          // # of threshold-equal keys to KEEP
    const uint32 ceq = hist[b3];         // # of threshold-equal keys total
    const uint32 t   = (p2 << 9) | b3;   // exact 31-bit threshold key

    // ---- tie-break (rare): keep the k3 lowest-index elements among equals ----
    uint32 idx_cut = 0xFFFFFFFFu;
    if (k3 < ceq) {                      // uniform branch (shared values)
        uint32* tied = hist;             // reuse histogram storage
        __syncthreads();                 // everyone finished reading hist
#pragma unroll
        for (int e = 0; e < 16; ++e) {
            if (key[e] == t) {
                uint32 pos = atomicAdd(&sh_cnt, 1u);
                if (pos < 2048u) {
                    int j = e >> 2, l = e & 3;
                    tied[pos] = (uint32)(4 * (j * TPB + tid) + l);
                }
            }
        }
        __syncthreads();
        uint32 c2 = min(sh_cnt, 2048u);
        for (uint32 i = tid; i < c2; i += TPB) {
            uint32 my = tied[i];
            uint32 r = 0;
            for (uint32 jj = 0; jj < c2; ++jj) r += (tied[jj] < my) ? 1u : 0u;
            if (r == k3 - 1u) sh_idxcut = my;   // the k3-th smallest tied index
        }
        __syncthreads();
        idx_cut = sh_idxcut;
    }

    // ---- epilogue: blend + store ----
    const float om = 1.0f - tau;
#pragma unroll
    for (int j = 0; j < 4; ++j) {
        float4 o;
        const float* pv = reinterpret_cast<const float*>(&v[j]);
        float* po = reinterpret_cast<float*>(&o);
#pragma unroll
        for (int l = 0; l < 4; ++l) {
            int e = j * 4 + l;
            uint32 kb = key[e];
            uint32 eidx = (uint32)(4 * (j * TPB + tid) + l);
            bool keep = (kb > t) || (kb == t && eidx <= idx_cut);
            float xv = pv[l];
            po[l] = keep ? (xv * tau + xv * om) : (xv * om);
        }
        orw[tid + j * TPB] = o;
    }
}

extern "C" void kernel_launch(void* const* d_in, const int* in_sizes, int n_in,
                              void* d_out, int out_size, void* d_ws, size_t ws_size,
                              hipStream_t stream)
{
    (void)n_in; (void)out_size; (void)d_ws; (void)ws_size;
    const float* x   = (const float*)d_in[0];
    const float* tau = (const float*)d_in[1];
    const int*   kp  = (const int*)d_in[2];
    float*       out = (float*)d_out;
    const int nrows  = in_sizes[0] / HW;   // 32*256 = 8192 rows of 4096
    topk_blend_kernel<<<nrows, TPB, 0, stream>>>(x, tau, kp, out, nrows);
}